// Round 1
// baseline (48.401 us; speedup 1.0000x reference)
//
#include <hip/hip_runtime.h>
#include <hip/hip_bf16.h>

#define NB   32      // batch N
#define NRR  48      // rows NR
#define TT   2048    // temporal length T
#define DD   256     // d_model
#define QQ   32      // query points
#define SS   4       // subpoints

// One block per (n, r) row. 256 threads = one per channel d.
__global__ __launch_bounds__(256) void pd_kernel(
    const float* __restrict__ pro,     // (N, NR, D)
    const float* __restrict__ feat,    // (N, T, D)
    const float* __restrict__ sp,      // (N, NR, Q)
    const float* __restrict__ w_bo, const float* __restrict__ b_bo,
    const float* __restrict__ w_co, const float* __restrict__ b_co,
    const float* __restrict__ w_bw, const float* __restrict__ b_bw,
    const float* __restrict__ w_cw, const float* __restrict__ b_cw,
    float* __restrict__ out)           // (Q, N*NR, D)
{
    const int row  = blockIdx.x;       // n*NR + r
    const int n    = row / NRR;
    const int d    = threadIdx.x;      // 0..255
    const int lane = d & 63;
    const int wv   = d >> 6;

    // ---- 16 dot products of pro[row,:] with the 4x4 weight rows ----
    const float p = pro[(size_t)row * DD + d];

    float acc[16];
#pragma unroll
    for (int s = 0; s < 4; ++s) {
        acc[s]      = p * w_bo[s * DD + d];
        acc[4 + s]  = p * w_co[s * DD + d];
        acc[8 + s]  = p * w_bw[s * DD + d];
        acc[12 + s] = p * w_cw[s * DD + d];
    }
    // 64-lane butterfly reduce (wave = 64 on CDNA)
#pragma unroll
    for (int st = 1; st < 64; st <<= 1) {
#pragma unroll
        for (int k = 0; k < 16; ++k)
            acc[k] += __shfl_xor(acc[k], st, 64);
    }

    __shared__ float red[4][16];
    if (lane == 0) {
#pragma unroll
        for (int k = 0; k < 16; ++k) red[wv][k] = acc[k];
    }
    __syncthreads();

    float dot[16];
#pragma unroll
    for (int k = 0; k < 16; ++k)
        dot[k] = red[0][k] + red[1][k] + red[2][k] + red[3][k];

    float bo[4], co[4], bw[4], cw[4];
#pragma unroll
    for (int s = 0; s < 4; ++s) {
        bo[s] = dot[s]      + b_bo[s];
        co[s] = dot[4 + s]  + b_co[s];
        bw[s] = dot[8 + s]  + b_bw[s];
        cw[s] = dot[12 + s] + b_cw[s];
    }
    // softmax over s for the two weight quads (max-subtracted, like jax.nn.softmax)
    {
        float mb = fmaxf(fmaxf(bw[0], bw[1]), fmaxf(bw[2], bw[3]));
        float mc = fmaxf(fmaxf(cw[0], cw[1]), fmaxf(cw[2], cw[3]));
        float sb = 0.f, sc = 0.f;
#pragma unroll
        for (int s = 0; s < 4; ++s) { bw[s] = expf(bw[s] - mb); sb += bw[s]; }
#pragma unroll
        for (int s = 0; s < 4; ++s) { cw[s] = expf(cw[s] - mc); sc += cw[s]; }
        const float rb = 1.f / sb, rc = 1.f / sc;
#pragma unroll
        for (int s = 0; s < 4; ++s) { bw[s] *= rb; cw[s] *= rc; }
    }

    // ---- gather + mix loop over query points ----
    const float* fn  = feat + (size_t)n * TT * DD + d;   // column d of features[n]
    const float* spr = sp + (size_t)row * QQ;
    const float  inv_w = 1.0f / 2048.0f;

    for (int q = 0; q < QQ; ++q) {
        const bool  isB   = (q < 4);
        const float point = spr[q];                      // uniform across block
        float o = 0.f;
#pragma unroll
        for (int s = 0; s < 4; ++s) {
            const float off = (isB ? bo[s] : co[s]) * inv_w;
            const float loc = fminf(fmaxf(point + off, 0.f), 1.f);
            const float px  = loc * (float)TT - 0.5f;    // pixel-space x
            const float x0f = floorf(px);
            const float w1  = px - x0f;                  // right-neighbor weight
            const int   x0  = (int)x0f;                  // in [-1, 2047]
            const float g0  = (x0 >= 0)     ? fn[(size_t)x0 * DD]       : 0.f;
            const float g1  = (x0 + 1 < TT) ? fn[(size_t)(x0 + 1) * DD] : 0.f;
            const float wgt = isB ? bw[s] : cw[s];
            o += wgt * 0.5f * ((1.f - w1) * g0 + w1 * g1);
        }
        out[((size_t)q * (NB * NRR) + row) * DD + d] = o;
    }
}

extern "C" void kernel_launch(void* const* d_in, const int* in_sizes, int n_in,
                              void* d_out, int out_size, void* d_ws, size_t ws_size,
                              hipStream_t stream) {
    const float* pro  = (const float*)d_in[0];
    const float* feat = (const float*)d_in[1];
    const float* sp   = (const float*)d_in[2];
    const float* w_bo = (const float*)d_in[3];
    const float* b_bo = (const float*)d_in[4];
    const float* w_co = (const float*)d_in[5];
    const float* b_co = (const float*)d_in[6];
    const float* w_bw = (const float*)d_in[7];
    const float* b_bw = (const float*)d_in[8];
    const float* w_cw = (const float*)d_in[9];
    const float* b_cw = (const float*)d_in[10];
    float* out = (float*)d_out;

    pd_kernel<<<NB * NRR, 256, 0, stream>>>(
        pro, feat, sp, w_bo, b_bo, w_co, b_co, w_bw, b_bw, w_cw, b_cw, out);
}

// Round 2
// 41.033 us; speedup vs baseline: 1.1796x; 1.1796x over previous
//
#include <hip/hip_runtime.h>
#include <hip/hip_bf16.h>

#define NB   32      // batch N
#define NRR  48      // rows NR
#define TT   2048    // temporal length T
#define DD   256     // d_model
#define QQ   32      // query points
#define ROWS (NB * NRR)   // 1536 total rows
#define NXCD 8

// One block per (n, r) row; 256 threads = 4 waves.
// Each wave independently covers all 256 channels as float4 (lane*4),
// computes the 16 tiny dots redundantly (wave-local butterfly, no LDS),
// and processes 8 of the 32 query points.
__global__ __launch_bounds__(256) void pd_kernel(
    const float* __restrict__ pro,     // (N, NR, D)
    const float* __restrict__ feat,    // (N, T, D)
    const float* __restrict__ sp,      // (N, NR, Q)
    const float* __restrict__ w_bo, const float* __restrict__ b_bo,
    const float* __restrict__ w_co, const float* __restrict__ b_co,
    const float* __restrict__ w_bw, const float* __restrict__ b_bw,
    const float* __restrict__ w_cw, const float* __restrict__ b_cw,
    float* __restrict__ out)           // (Q, ROWS, D)
{
    // XCD-aware swizzle: hardware block b -> XCD b%8. Give XCD k the
    // contiguous row range [k*192, (k+1)*192) = n in [4k, 4k+4) so the
    // concurrently-resident blocks on one XCD share 1-2 feature slices
    // (2-4 MiB) inside the 4 MiB per-XCD L2.
    const int bid = blockIdx.x;
    const int row = (bid & (NXCD - 1)) * (ROWS / NXCD) + (bid >> 3);
    const int n    = row / NRR;
    const int lane = threadIdx.x & 63;
    const int wv   = threadIdx.x >> 6;      // wave 0..3
    const int d4   = lane << 2;             // channel base (float4 per lane)

    // ---- 16 dot products of pro[row,:] with the 4x4 weight rows ----
    const float4 p = *reinterpret_cast<const float4*>(pro + (size_t)row * DD + d4);

    float acc[16];
#pragma unroll
    for (int s = 0; s < 4; ++s) {
        float4 w;
        w = *reinterpret_cast<const float4*>(w_bo + s * DD + d4);
        acc[s]      = p.x * w.x + p.y * w.y + p.z * w.z + p.w * w.w;
        w = *reinterpret_cast<const float4*>(w_co + s * DD + d4);
        acc[4 + s]  = p.x * w.x + p.y * w.y + p.z * w.z + p.w * w.w;
        w = *reinterpret_cast<const float4*>(w_bw + s * DD + d4);
        acc[8 + s]  = p.x * w.x + p.y * w.y + p.z * w.z + p.w * w.w;
        w = *reinterpret_cast<const float4*>(w_cw + s * DD + d4);
        acc[12 + s] = p.x * w.x + p.y * w.y + p.z * w.z + p.w * w.w;
    }
    // 64-lane butterfly reduce; every lane ends with the full dot values.
#pragma unroll
    for (int st = 1; st < 64; st <<= 1) {
#pragma unroll
        for (int k = 0; k < 16; ++k)
            acc[k] += __shfl_xor(acc[k], st, 64);
    }

    float bo[4], co[4], bw[4], cw[4];
#pragma unroll
    for (int s = 0; s < 4; ++s) {
        bo[s] = acc[s]      + b_bo[s];
        co[s] = acc[4 + s]  + b_co[s];
        bw[s] = acc[8 + s]  + b_bw[s];
        cw[s] = acc[12 + s] + b_cw[s];
    }
    // softmax over s (max-subtracted), then fold the 0.5 row weight in.
    {
        float mb = fmaxf(fmaxf(bw[0], bw[1]), fmaxf(bw[2], bw[3]));
        float mc = fmaxf(fmaxf(cw[0], cw[1]), fmaxf(cw[2], cw[3]));
        float sb = 0.f, sc = 0.f;
#pragma unroll
        for (int s = 0; s < 4; ++s) { bw[s] = expf(bw[s] - mb); sb += bw[s]; }
#pragma unroll
        for (int s = 0; s < 4; ++s) { cw[s] = expf(cw[s] - mc); sc += cw[s]; }
        const float rb = 0.5f / sb, rc = 0.5f / sc;   // 0.5 = y=-1 row weight
#pragma unroll
        for (int s = 0; s < 4; ++s) { bw[s] *= rb; cw[s] *= rc; }
    }

    // ---- gather + mix: wave wv handles q = 8*wv .. 8*wv+7 ----
    const float* fn  = feat + (size_t)n * TT * DD + d4;  // lane's 16B column
    const float* spr = sp + (size_t)row * QQ;
    const float  inv_w = 1.0f / 2048.0f;

#pragma unroll
    for (int j = 0; j < 8; ++j) {
        const int   q     = (wv << 3) + j;
        const bool  isB   = (q < 4);                 // wave-uniform
        const float point = spr[q];
        float4 o = {0.f, 0.f, 0.f, 0.f};
#pragma unroll
        for (int s = 0; s < 4; ++s) {
            const float off = (isB ? bo[s] : co[s]) * inv_w;
            const float loc = fminf(fmaxf(point + off, 0.f), 1.f);
            const float px  = loc * (float)TT - 0.5f;
            const float x0f = floorf(px);
            const float w1  = px - x0f;              // right-neighbor weight
            const int   x0  = (int)x0f;              // in [-1, 2047]
            const float wgt = isB ? bw[s] : cw[s];
            const float c0  = wgt * (1.f - w1);
            const float c1  = wgt * w1;
            const float* base = fn + (size_t)x0 * DD;
            if (x0 >= 0) {
                const float4 g0 = *reinterpret_cast<const float4*>(base);
                o.x += c0 * g0.x; o.y += c0 * g0.y;
                o.z += c0 * g0.z; o.w += c0 * g0.w;
            }
            if (x0 + 1 < TT) {
                const float4 g1 = *reinterpret_cast<const float4*>(base + DD);
                o.x += c1 * g1.x; o.y += c1 * g1.y;
                o.z += c1 * g1.z; o.w += c1 * g1.w;
            }
        }
        *reinterpret_cast<float4*>(out + ((size_t)q * ROWS + row) * DD + d4) = o;
    }
}

extern "C" void kernel_launch(void* const* d_in, const int* in_sizes, int n_in,
                              void* d_out, int out_size, void* d_ws, size_t ws_size,
                              hipStream_t stream) {
    const float* pro  = (const float*)d_in[0];
    const float* feat = (const float*)d_in[1];
    const float* sp   = (const float*)d_in[2];
    const float* w_bo = (const float*)d_in[3];
    const float* b_bo = (const float*)d_in[4];
    const float* w_co = (const float*)d_in[5];
    const float* b_co = (const float*)d_in[6];
    const float* w_bw = (const float*)d_in[7];
    const float* b_bw = (const float*)d_in[8];
    const float* w_cw = (const float*)d_in[9];
    const float* b_cw = (const float*)d_in[10];
    float* out = (float*)d_out;

    pd_kernel<<<ROWS, 256, 0, stream>>>(
        pro, feat, sp, w_bo, b_bo, w_co, b_co, w_bw, b_bw, w_cw, b_cw, out);
}

// Round 4
// 29.602 us; speedup vs baseline: 1.6351x; 1.3862x over previous
//
#include <hip/hip_runtime.h>
#include <hip/hip_bf16.h>

#define NB   32      // batch N
#define NRR  48      // rows NR
#define TT   2048    // temporal length T
#define DD   256     // d_model
#define QQ   32      // query points
#define ROWS (NB * NRR)   // 1536 total rows
#define NXCD 8

typedef float f32x4 __attribute__((ext_vector_type(4)));

// One block per (n, r) row; 256 threads = 4 waves.
// Each wave independently covers all 256 channels as float4 (lane*4),
// computes the 16 tiny dots redundantly (wave-local butterfly, no LDS),
// and processes 8 of the 32 query points. All gather loads are
// UNCONDITIONAL (clamped index, coefficient masked to 0 when OOB) so the
// 8 loads per query point cluster into one vmem burst (MLP=8) instead of
// serializing behind per-load branches.
__global__ __launch_bounds__(256) void pd_kernel(
    const float* __restrict__ pro,     // (N, NR, D)
    const float* __restrict__ feat,    // (N, T, D)
    const float* __restrict__ sp,      // (N, NR, Q)
    const float* __restrict__ w_bo, const float* __restrict__ b_bo,
    const float* __restrict__ w_co, const float* __restrict__ b_co,
    const float* __restrict__ w_bw, const float* __restrict__ b_bw,
    const float* __restrict__ w_cw, const float* __restrict__ b_cw,
    float* __restrict__ out)           // (Q, ROWS, D)
{
    // XCD-aware swizzle: hardware block b -> XCD b%8. Give XCD k rows
    // [k*192, (k+1)*192) = n in [4k, 4k+4) so resident blocks on one XCD
    // share 1-2 feature slices (2-4 MiB) inside the 4 MiB per-XCD L2.
    const int bid = blockIdx.x;
    const int row = (bid & (NXCD - 1)) * (ROWS / NXCD) + (bid >> 3);
    const int n    = row / NRR;
    const int lane = threadIdx.x & 63;
    const int wv   = threadIdx.x >> 6;      // wave 0..3
    const int d4   = lane << 2;             // channel base (float4 per lane)

    // ---- 16 dot products of pro[row,:] with the 4x4 weight rows ----
    const f32x4 p = *reinterpret_cast<const f32x4*>(pro + (size_t)row * DD + d4);

    float acc[16];
#pragma unroll
    for (int s = 0; s < 4; ++s) {
        f32x4 w;
        w = *reinterpret_cast<const f32x4*>(w_bo + s * DD + d4);
        acc[s]      = p.x * w.x + p.y * w.y + p.z * w.z + p.w * w.w;
        w = *reinterpret_cast<const f32x4*>(w_co + s * DD + d4);
        acc[4 + s]  = p.x * w.x + p.y * w.y + p.z * w.z + p.w * w.w;
        w = *reinterpret_cast<const f32x4*>(w_bw + s * DD + d4);
        acc[8 + s]  = p.x * w.x + p.y * w.y + p.z * w.z + p.w * w.w;
        w = *reinterpret_cast<const f32x4*>(w_cw + s * DD + d4);
        acc[12 + s] = p.x * w.x + p.y * w.y + p.z * w.z + p.w * w.w;
    }
    // 64-lane butterfly reduce; every lane ends with the full dot values.
#pragma unroll
    for (int st = 1; st < 64; st <<= 1) {
#pragma unroll
        for (int k = 0; k < 16; ++k)
            acc[k] += __shfl_xor(acc[k], st, 64);
    }

    float bo[4], co[4], bw[4], cw[4];
#pragma unroll
    for (int s = 0; s < 4; ++s) {
        bo[s] = acc[s]      + b_bo[s];
        co[s] = acc[4 + s]  + b_co[s];
        bw[s] = acc[8 + s]  + b_bw[s];
        cw[s] = acc[12 + s] + b_cw[s];
    }
    // softmax over s (max-subtracted), then fold the 0.5 row weight in.
    {
        float mb = fmaxf(fmaxf(bw[0], bw[1]), fmaxf(bw[2], bw[3]));
        float mc = fmaxf(fmaxf(cw[0], cw[1]), fmaxf(cw[2], cw[3]));
        float sb = 0.f, sc = 0.f;
#pragma unroll
        for (int s = 0; s < 4; ++s) { bw[s] = expf(bw[s] - mb); sb += bw[s]; }
#pragma unroll
        for (int s = 0; s < 4; ++s) { cw[s] = expf(cw[s] - mc); sc += cw[s]; }
        const float rb = 0.5f / sb, rc = 0.5f / sc;   // 0.5 = y=-1 row weight
#pragma unroll
        for (int s = 0; s < 4; ++s) { bw[s] *= rb; cw[s] *= rc; }
    }

    // ---- gather + mix: wave wv handles q = 8*wv .. 8*wv+7 ----
    const float* fn  = feat + (size_t)n * TT * DD + d4;  // lane's 16B column
    const float* spr = sp + (size_t)row * QQ;
    const float  inv_w = 1.0f / 2048.0f;

#pragma unroll
    for (int j = 0; j < 8; ++j) {
        const int   q     = (wv << 3) + j;
        const bool  isB   = (q < 4);                 // wave-uniform
        const float point = spr[q];

        f32x4 g[8];
        float cc[8];
#pragma unroll
        for (int s = 0; s < 4; ++s) {
            const float off = (isB ? bo[s] : co[s]) * inv_w;
            const float loc = fminf(fmaxf(point + off, 0.f), 1.f);
            const float px  = loc * (float)TT - 0.5f;
            const float x0f = floorf(px);
            const float w1  = px - x0f;              // right-neighbor weight
            const int   x0  = (int)x0f;              // in [-1, 2047]
            const int   x0c = x0 < 0 ? 0 : x0;       // clamped indices
            const int   x1c = x0 + 1 > TT - 1 ? TT - 1 : x0 + 1;
            const float wgt = isB ? bw[s] : cw[s];
            cc[2 * s]     = (x0 >= 0)     ? wgt * (1.f - w1) : 0.f;
            cc[2 * s + 1] = (x0 + 1 < TT) ? wgt * w1         : 0.f;
            g[2 * s]     = *reinterpret_cast<const f32x4*>(fn + (size_t)x0c * DD);
            g[2 * s + 1] = *reinterpret_cast<const f32x4*>(fn + (size_t)x1c * DD);
        }

        f32x4 o = {0.f, 0.f, 0.f, 0.f};
#pragma unroll
        for (int k = 0; k < 8; ++k)
            o += cc[k] * g[k];
        // streamed output, never re-read: keep it out of L2
        __builtin_nontemporal_store(o,
            reinterpret_cast<f32x4*>(out + ((size_t)q * ROWS + row) * DD + d4));
    }
}

extern "C" void kernel_launch(void* const* d_in, const int* in_sizes, int n_in,
                              void* d_out, int out_size, void* d_ws, size_t ws_size,
                              hipStream_t stream) {
    const float* pro  = (const float*)d_in[0];
    const float* feat = (const float*)d_in[1];
    const float* sp   = (const float*)d_in[2];
    const float* w_bo = (const float*)d_in[3];
    const float* b_bo = (const float*)d_in[4];
    const float* w_co = (const float*)d_in[5];
    const float* b_co = (const float*)d_in[6];
    const float* w_bw = (const float*)d_in[7];
    const float* b_bw = (const float*)d_in[8];
    const float* w_cw = (const float*)d_in[9];
    const float* b_cw = (const float*)d_in[10];
    float* out = (float*)d_out;

    pd_kernel<<<ROWS, 256, 0, stream>>>(
        pro, feat, sp, w_bo, b_bo, w_co, b_co, w_bw, b_bw, w_cw, b_cw, out);
}